// Round 8
// baseline (310.813 us; speedup 1.0000x reference)
//
#include <hip/hip_runtime.h>
#include <hip/hip_fp16.h>

#define N_NODES   50000
#define N_EDGES   800000
#define IN_FEAT   128
#define N_CLASSES 64
#define LDS_PAD   132   // 128 + 4 floats: row-to-row bank stride = 4, float4-aligned

// ---------------------------------------------------------------------------
// CSR build: histogram of targets, fused single-block scan, fill adjacency.
// ---------------------------------------------------------------------------
__global__ void count_kernel(const int* __restrict__ col, int* __restrict__ cnt, int e) {
    int i = blockIdx.x * blockDim.x + threadIdx.x;
    if (i < e) atomicAdd(&cnt[col[i]], 1);
}

// One block, 1024 threads. Thread t owns a contiguous 49-element chunk:
// pass1 local sum -> LDS Hillis-Steele scan (one 1024-entry scan) -> pass2
// write exclusive prefixes + dinv. Replaces the 3-kernel two-level scan.
__global__ __launch_bounds__(1024) void scan_fused_kernel(const int* __restrict__ cnt,
                                                          int* __restrict__ rowptr,
                                                          int* __restrict__ cursor,
                                                          float* __restrict__ dinv, int n) {
    __shared__ int ssum[1024];
    int t = threadIdx.x;
    const int C = (n + 1023) / 1024;  // 49
    int base = t * C;
    int end  = min(base + C, n);

    int local = 0;
    for (int i = base; i < end; ++i) local += cnt[i];
    ssum[t] = local;
    __syncthreads();
    for (int off = 1; off < 1024; off <<= 1) {
        int add = (t >= off) ? ssum[t - off] : 0;
        __syncthreads();
        ssum[t] += add;
        __syncthreads();
    }
    int run = ssum[t] - local;  // exclusive prefix at chunk start
    for (int i = base; i < end; ++i) {
        int v = cnt[i];
        rowptr[i] = run;
        cursor[i] = run;
        dinv[i]   = rsqrtf((float)(v + 1));  // +1 self loop
        run += v;
    }
    if (t == 1023) rowptr[n] = ssum[1023];
}

__global__ void fill_kernel(const int* __restrict__ row, const int* __restrict__ col,
                            int* __restrict__ cursor, int* __restrict__ adj, int e) {
    int i = blockIdx.x * blockDim.x + threadIdx.x;
    if (i < e) {
        int c = col[i];
        int pos = atomicAdd(&cursor[c], 1);
        adj[pos] = row[i];
    }
}

// ---------------------------------------------------------------------------
// Tiled u = dinv .* (x @ W^T), fp16 output.  64x64 tile per 256-thread block;
// x-tile and W in LDS (pad 132); 4x4 register tile per thread.
// ---------------------------------------------------------------------------
__global__ __launch_bounds__(256) void gemm_kernel(const float* __restrict__ x,
                                                   const float* __restrict__ W,
                                                   const float* __restrict__ dinv,
                                                   __half* __restrict__ u, int n) {
    __shared__ float xs[64][LDS_PAD];
    __shared__ float ws[64][LDS_PAD];
    int t = threadIdx.x;
    int rowbase = blockIdx.x * 64;

    for (int i = t; i < 64 * 32; i += 256) {
        int r  = i >> 5;
        int kk = i & 31;
        *(float4*)(&ws[r][kk * 4]) = *(const float4*)(W + (size_t)r * IN_FEAT + kk * 4);
        int gr = rowbase + r;
        float4 v = make_float4(0.f, 0.f, 0.f, 0.f);
        if (gr < n) v = *(const float4*)(x + (size_t)gr * IN_FEAT + kk * 4);
        *(float4*)(&xs[r][kk * 4]) = v;
    }
    __syncthreads();

    int rg = t >> 4;
    int cg = t & 15;
    float acc[4][4] = {};

    for (int kk = 0; kk < 32; ++kk) {
        float4 a[4], bb[4];
#pragma unroll
        for (int i = 0; i < 4; ++i) a[i]  = *(float4*)(&xs[rg + 16 * i][kk * 4]);
#pragma unroll
        for (int j = 0; j < 4; ++j) bb[j] = *(float4*)(&ws[cg + 16 * j][kk * 4]);
#pragma unroll
        for (int i = 0; i < 4; ++i)
#pragma unroll
            for (int j = 0; j < 4; ++j)
                acc[i][j] += a[i].x * bb[j].x + a[i].y * bb[j].y +
                             a[i].z * bb[j].z + a[i].w * bb[j].w;
    }

#pragma unroll
    for (int i = 0; i < 4; ++i) {
        int gr = rowbase + rg + 16 * i;
        if (gr < n) {
            float d = dinv[gr];
#pragma unroll
            for (int j = 0; j < 4; ++j)
                u[(size_t)gr * N_CLASSES + cg + 16 * j] = __float2half(d * acc[i][j]);
        }
    }
}

// ---------------------------------------------------------------------------
// Hop, 2 edges per gather instruction.  fp16 row = 128B = 32 lanes x __half2.
// Wave halves process even/odd elements of the virtual list [node] ++ adj[s..e2):
//   lane<32  -> elements j = 0,2,4,...   (features 2*hl, 2*hl+1)
//   lane>=32 -> elements j = 1,3,5,...
// One instruction gathers 2 rows -> half the serial chain, 2x loads in flight.
// __shfl_xor(32) combines halves; half 0 stores coalesced.
// mode 0: w1 = fp16(dinv^2 * sum);  mode 1: out = fp32(dinv * sum + bias).
// ---------------------------------------------------------------------------
__global__ __launch_bounds__(256) void hop_sum_kernel(const int* __restrict__ rowptr,
                                                      const int* __restrict__ adj,
                                                      const float* __restrict__ dinv,
                                                      const __half2* __restrict__ yin2,
                                                      __half2* __restrict__ yout_h2,
                                                      float* __restrict__ yout_f,
                                                      const float* __restrict__ bias,
                                                      int mode, int n) {
    int sub    = threadIdx.x >> 6;
    int lane   = threadIdx.x & 63;
    int halfid = lane >> 5;
    int hl     = lane & 31;
    int node   = blockIdx.x * 4 + sub;
    if (node >= n) return;

    int s = rowptr[node];
    int L = rowptr[node + 1] - s + 1;  // virtual list length: self + in-edges

    float ax = 0.f, ay = 0.f;
    int j = halfid;
    for (; j + 6 < L; j += 8) {
        int r0 = (j == 0) ? node : adj[s + j - 1];
        int r1 = adj[s + j + 1];
        int r2 = adj[s + j + 3];
        int r3 = adj[s + j + 5];
        float2 v0 = __half22float2(yin2[(size_t)r0 * 32 + hl]);
        float2 v1 = __half22float2(yin2[(size_t)r1 * 32 + hl]);
        float2 v2 = __half22float2(yin2[(size_t)r2 * 32 + hl]);
        float2 v3 = __half22float2(yin2[(size_t)r3 * 32 + hl]);
        ax += (v0.x + v1.x) + (v2.x + v3.x);
        ay += (v0.y + v1.y) + (v2.y + v3.y);
    }
    for (; j < L; j += 2) {
        int r = (j == 0) ? node : adj[s + j - 1];
        float2 v = __half22float2(yin2[(size_t)r * 32 + hl]);
        ax += v.x;
        ay += v.y;
    }

    float tx = ax + __shfl_xor(ax, 32);
    float ty = ay + __shfl_xor(ay, 32);

    if (halfid == 0) {
        float d = dinv[node];
        if (mode == 0) {
            float dd = d * d;
            yout_h2[(size_t)node * 32 + hl] = __halves2half2(__float2half(dd * tx), __float2half(dd * ty));
        } else {
            float2 bb = *(const float2*)(bias + 2 * hl);
            float2 o  = make_float2(d * tx + bb.x, d * ty + bb.y);
            *(float2*)(yout_f + (size_t)node * 64 + 2 * hl) = o;
        }
    }
}

// ---------------------------------------------------------------------------
extern "C" void kernel_launch(void* const* d_in, const int* in_sizes, int n_in,
                              void* d_out, int out_size, void* d_ws, size_t ws_size,
                              hipStream_t stream) {
    const float* x     = (const float*)d_in[0];
    const int*   edges = (const int*)d_in[1];   // int64 ref -> int32 device, [2, E] flat
    const float* W     = (const float*)d_in[2]; // [64, 128]
    const float* b     = (const float*)d_in[3]; // [64]
    float*       out   = (float*)d_out;         // [N, 64]

    const int* row = edges;            // sources
    const int* col = edges + N_EDGES;  // targets

    char* ws = (char*)d_ws;
    int*     cnt    = (int*)(ws + 0);
    int*     rowptr = (int*)(ws + 256 * 1024);
    int*     cursor = (int*)(ws + 512 * 1024);
    float*   dinv   = (float*)(ws + 768 * 1024);
    int*     adj    = (int*)(ws + 1024 * 1024);          // 3.2 MB
    __half*  u      = (__half*)(ws + 8 * 1024 * 1024);   // 6.4 MB fp16
    __half*  w1     = (__half*)(ws + 16 * 1024 * 1024);  // 6.4 MB fp16

    // CSR build + dinv
    hipMemsetAsync(cnt, 0, N_NODES * sizeof(int), stream);
    count_kernel<<<(N_EDGES + 255) / 256, 256, 0, stream>>>(col, cnt, N_EDGES);
    scan_fused_kernel<<<1, 1024, 0, stream>>>(cnt, rowptr, cursor, dinv, N_NODES);
    fill_kernel<<<(N_EDGES + 255) / 256, 256, 0, stream>>>(row, col, cursor, adj, N_EDGES);

    // u = D^{-1/2} (x @ W^T)  (fp16 storage)
    gemm_kernel<<<(N_NODES + 63) / 64, 256, 0, stream>>>(x, W, dinv, u, N_NODES);

    // hop1: w1 = D^{-1} (A+I) u ;  hop2: out = D^{-1/2} (A+I) w1 + b
    hop_sum_kernel<<<(N_NODES + 3) / 4, 256, 0, stream>>>(rowptr, adj, dinv,
        (const __half2*)u, (__half2*)w1, nullptr, nullptr, 0, N_NODES);
    hop_sum_kernel<<<(N_NODES + 3) / 4, 256, 0, stream>>>(rowptr, adj, dinv,
        (const __half2*)w1, nullptr, out, b, 1, N_NODES);
}

// Round 12
// 158.702 us; speedup vs baseline: 1.9585x; 1.9585x over previous
//
#include <hip/hip_runtime.h>
#include <hip/hip_fp16.h>

#define N_NODES   50000
#define N_EDGES   800000
#define IN_FEAT   128
#define N_CLASSES 64
#define LDS_PAD   132   // 128 + 4 floats: row-to-row bank stride = 4, float4-aligned

// ---------------------------------------------------------------------------
// CSR build, rank-trick version (one atomic pass instead of two):
//   pass1: rank[i] = atomicAdd(&cnt[col[i]], 1)   (count + rank-in-bucket)
//   scan : rowptr = exclusive_scan(cnt)           (two-level trio)
//   pass2: adj[rowptr[col[i]] + rank[i]] = row[i] (atomic-free scatter)
// ---------------------------------------------------------------------------
__global__ void count_rank_kernel(const int* __restrict__ col, int* __restrict__ cnt,
                                  int* __restrict__ rank, int e) {
    int i = blockIdx.x * blockDim.x + threadIdx.x;
    if (i < e) rank[i] = atomicAdd(&cnt[col[i]], 1);
}

__global__ __launch_bounds__(256) void block_sum_kernel(const int* __restrict__ cnt,
                                                        int* __restrict__ bsum, int n) {
    __shared__ int s[256];
    int t = threadIdx.x;
    int i = blockIdx.x * 256 + t;
    s[t] = (i < n) ? cnt[i] : 0;
    __syncthreads();
    for (int off = 128; off > 0; off >>= 1) {
        if (t < off) s[t] += s[t + off];
        __syncthreads();
    }
    if (t == 0) bsum[blockIdx.x] = s[0];
}

__global__ __launch_bounds__(256) void scan_bsum_kernel(int* __restrict__ bsum, int nb) {
    __shared__ int s[256];
    int t = threadIdx.x;
    s[t] = (t < nb) ? bsum[t] : 0;
    __syncthreads();
    for (int off = 1; off < 256; off <<= 1) {
        int add = (t >= off) ? s[t - off] : 0;
        __syncthreads();
        s[t] += add;
        __syncthreads();
    }
    if (t < nb) bsum[t] = s[t];  // inclusive sums
}

__global__ __launch_bounds__(256) void apply_scan_kernel(const int* __restrict__ cnt,
                                                         const int* __restrict__ bsum,
                                                         int* __restrict__ rowptr,
                                                         float* __restrict__ dinv, int n) {
    __shared__ int s[256];
    int b = blockIdx.x, t = threadIdx.x;
    int i = b * 256 + t;
    int v = (i < n) ? cnt[i] : 0;
    s[t] = v;
    __syncthreads();
    for (int off = 1; off < 256; off <<= 1) {
        int add = (t >= off) ? s[t - off] : 0;
        __syncthreads();
        s[t] += add;
        __syncthreads();
    }
    int boff = (b > 0) ? bsum[b - 1] : 0;
    if (i < n) {
        rowptr[i] = boff + s[t] - v;                 // exclusive prefix
        dinv[i]   = rsqrtf((float)(v + 1));          // +1 self loop
    }
    if (i == n - 1) rowptr[n] = boff + s[t];
}

__global__ void scatter_kernel(const int* __restrict__ row, const int* __restrict__ col,
                               const int* __restrict__ rank, const int* __restrict__ rowptr,
                               int* __restrict__ adj, int e) {
    int i = blockIdx.x * blockDim.x + threadIdx.x;
    if (i < e) adj[rowptr[col[i]] + rank[i]] = row[i];
}

// ---------------------------------------------------------------------------
// Tiled u = dinv .* (x @ W^T), fp16 output.  64x64 tile per 256-thread block;
// x-tile and W in LDS (pad 132); 4x4 register tile per thread.
// ---------------------------------------------------------------------------
__global__ __launch_bounds__(256) void gemm_kernel(const float* __restrict__ x,
                                                   const float* __restrict__ W,
                                                   const float* __restrict__ dinv,
                                                   __half* __restrict__ u, int n) {
    __shared__ float xs[64][LDS_PAD];
    __shared__ float ws[64][LDS_PAD];
    int t = threadIdx.x;
    int rowbase = blockIdx.x * 64;

    for (int i = t; i < 64 * 32; i += 256) {
        int r  = i >> 5;
        int kk = i & 31;
        *(float4*)(&ws[r][kk * 4]) = *(const float4*)(W + (size_t)r * IN_FEAT + kk * 4);
        int gr = rowbase + r;
        float4 v = make_float4(0.f, 0.f, 0.f, 0.f);
        if (gr < n) v = *(const float4*)(x + (size_t)gr * IN_FEAT + kk * 4);
        *(float4*)(&xs[r][kk * 4]) = v;
    }
    __syncthreads();

    int rg = t >> 4;
    int cg = t & 15;
    float acc[4][4] = {};

    for (int kk = 0; kk < 32; ++kk) {
        float4 a[4], bb[4];
#pragma unroll
        for (int i = 0; i < 4; ++i) a[i]  = *(float4*)(&xs[rg + 16 * i][kk * 4]);
#pragma unroll
        for (int j = 0; j < 4; ++j) bb[j] = *(float4*)(&ws[cg + 16 * j][kk * 4]);
#pragma unroll
        for (int i = 0; i < 4; ++i)
#pragma unroll
            for (int j = 0; j < 4; ++j)
                acc[i][j] += a[i].x * bb[j].x + a[i].y * bb[j].y +
                             a[i].z * bb[j].z + a[i].w * bb[j].w;
    }

#pragma unroll
    for (int i = 0; i < 4; ++i) {
        int gr = rowbase + rg + 16 * i;
        if (gr < n) {
            float d = dinv[gr];
#pragma unroll
            for (int j = 0; j < 4; ++j)
                u[(size_t)gr * N_CLASSES + cg + 16 * j] = __float2half(d * acc[i][j]);
        }
    }
}

// ---------------------------------------------------------------------------
// Pure-sum hop on fp16 tables, fp32 accumulate (R7's proven scalar version).
// mode 0: w1[c] = fp16( dinv^2 * ((A+I)u)[c] )
// mode 1: out[c] = fp32( dinv   * ((A+I)w1)[c] + bias )
// ---------------------------------------------------------------------------
__global__ __launch_bounds__(256) void hop_sum_kernel(const int* __restrict__ rowptr,
                                                      const int* __restrict__ adj,
                                                      const float* __restrict__ dinv,
                                                      const __half* __restrict__ yin,
                                                      __half* __restrict__ yout_h,
                                                      float* __restrict__ yout_f,
                                                      const float* __restrict__ bias,
                                                      int mode, int n) {
    int sub  = threadIdx.x >> 6;
    int lane = threadIdx.x & 63;
    int node = blockIdx.x * 4 + sub;
    if (node >= n) return;

    int s  = rowptr[node];
    int e2 = rowptr[node + 1];

    float acc = __half2float(yin[(size_t)node * N_CLASSES + lane]);  // self loop
    int k = s;
    for (; k + 7 < e2; k += 8) {
        float v0 = __half2float(yin[(size_t)adj[k + 0] * N_CLASSES + lane]);
        float v1 = __half2float(yin[(size_t)adj[k + 1] * N_CLASSES + lane]);
        float v2 = __half2float(yin[(size_t)adj[k + 2] * N_CLASSES + lane]);
        float v3 = __half2float(yin[(size_t)adj[k + 3] * N_CLASSES + lane]);
        float v4 = __half2float(yin[(size_t)adj[k + 4] * N_CLASSES + lane]);
        float v5 = __half2float(yin[(size_t)adj[k + 5] * N_CLASSES + lane]);
        float v6 = __half2float(yin[(size_t)adj[k + 6] * N_CLASSES + lane]);
        float v7 = __half2float(yin[(size_t)adj[k + 7] * N_CLASSES + lane]);
        acc += ((v0 + v1) + (v2 + v3)) + ((v4 + v5) + (v6 + v7));
    }
    for (; k < e2; ++k)
        acc += __half2float(yin[(size_t)adj[k] * N_CLASSES + lane]);

    float d = dinv[node];
    if (mode == 0) {
        yout_h[(size_t)node * N_CLASSES + lane] = __float2half(d * d * acc);
    } else {
        yout_f[(size_t)node * N_CLASSES + lane] = d * acc + bias[lane];
    }
}

// ---------------------------------------------------------------------------
extern "C" void kernel_launch(void* const* d_in, const int* in_sizes, int n_in,
                              void* d_out, int out_size, void* d_ws, size_t ws_size,
                              hipStream_t stream) {
    const float* x     = (const float*)d_in[0];
    const int*   edges = (const int*)d_in[1];   // int64 ref -> int32 device, [2, E] flat
    const float* W     = (const float*)d_in[2]; // [64, 128]
    const float* b     = (const float*)d_in[3]; // [64]
    float*       out   = (float*)d_out;         // [N, 64]

    const int* row = edges;            // sources
    const int* col = edges + N_EDGES;  // targets

    // Workspace map — ALL RANGES DISJOINT (the R5/R9/R10/R11 crashes were a
    // dinv/bsum overlap at the old offsets: dinv@768K needs 200,000B ->
    // reached 986,432, but bsum sat at 983,040 -> apply_scan raced its own
    // bsum reads against dinv writes -> garbage rowptr -> OOB adj write).
    //   cnt    [      0 ..  200,000)
    //   rowptr [262,144 ..  462,148)
    //   dinv   [524,288 ..  724,288)
    //   bsum   [786,432 ..  787,216)
    //   adj    [1,048,576 .. 4,248,576)
    //   rank   [4,718,592 .. 7,918,592)
    //   u      [8,388,608 .. 14,788,608)   fp16
    //   w1     [16,777,216 .. 23,177,216)  fp16
    char* ws = (char*)d_ws;
    int*     cnt    = (int*)(ws + 0);
    int*     rowptr = (int*)(ws + 256 * 1024);
    float*   dinv   = (float*)(ws + 512 * 1024);
    int*     bsum   = (int*)(ws + 768 * 1024);
    int*     adj    = (int*)(ws + 1024 * 1024);
    int*     rank   = (int*)(ws + 4608 * 1024);
    __half*  u      = (__half*)(ws + 8 * 1024 * 1024);
    __half*  w1     = (__half*)(ws + 16 * 1024 * 1024);

    const int nblk = (N_NODES + 255) / 256;  // 196

    // CSR build + dinv (rank trick: single atomic pass)
    hipMemsetAsync(cnt, 0, N_NODES * sizeof(int), stream);
    count_rank_kernel<<<(N_EDGES + 255) / 256, 256, 0, stream>>>(col, cnt, rank, N_EDGES);
    block_sum_kernel<<<nblk, 256, 0, stream>>>(cnt, bsum, N_NODES);
    scan_bsum_kernel<<<1, 256, 0, stream>>>(bsum, nblk);
    apply_scan_kernel<<<nblk, 256, 0, stream>>>(cnt, bsum, rowptr, dinv, N_NODES);
    scatter_kernel<<<(N_EDGES + 255) / 256, 256, 0, stream>>>(row, col, rank, rowptr, adj, N_EDGES);

    // u = D^{-1/2} (x @ W^T)  (fp16 storage)
    gemm_kernel<<<(N_NODES + 63) / 64, 256, 0, stream>>>(x, W, dinv, u, N_NODES);

    // hop1: w1 = D^{-1} (A+I) u ;  hop2: out = D^{-1/2} (A+I) w1 + b
    hop_sum_kernel<<<(N_NODES + 3) / 4, 256, 0, stream>>>(rowptr, adj, dinv,
        u, w1, nullptr, nullptr, 0, N_NODES);
    hop_sum_kernel<<<(N_NODES + 3) / 4, 256, 0, stream>>>(rowptr, adj, dinv,
        w1, nullptr, out, b, 1, N_NODES);
}